// Round 1
// 1729.211 us; speedup vs baseline: 1.0097x; 1.0097x over previous
//
#include <hip/hip_runtime.h>

#define N_NODES 50000
#define N_GENE  40000
#define N_GOID  10000
#define N_EDGES 800000
#define GOID_DIM 4096
#define GO_HID  1024
#define D_IN    512
#define HID1    512
#define HID2    256

typedef __bf16 bf16x8 __attribute__((ext_vector_type(8)));
typedef float v4f __attribute__((ext_vector_type(4)));

__device__ __forceinline__ unsigned short f2bf(float f) {
    unsigned int u = __float_as_uint(f);
    u += 0x7FFF + ((u >> 16) & 1);   // round-to-nearest-even
    return (unsigned short)(u >> 16);
}
__device__ __forceinline__ float b2f(unsigned short h) {
    return __uint_as_float(((unsigned int)h) << 16);
}
__device__ __forceinline__ unsigned int pack2(float a, float b) {
    return (unsigned int)f2bf(a) | ((unsigned int)f2bf(b) << 16);
}
// unpack 2 bf16 packed in a u32 -> floats (lo = bits<<16, hi = bits&0xffff0000)
__device__ __forceinline__ void unp2(unsigned int u, float& lo, float& hi) {
    lo = __uint_as_float(u << 16);
    hi = __uint_as_float(u & 0xffff0000u);
}
__device__ __forceinline__ void gload_lds16(const unsigned short* g, unsigned short* l) {
    __builtin_amdgcn_global_load_lds(
        (const __attribute__((address_space(1))) unsigned int*)g,
        (__attribute__((address_space(3))) unsigned int*)l, 16, 0, 0);
}

// ---------------- CSR build ----------------
__global__ void k_zero(int* __restrict__ p, int n) {
    int i = blockIdx.x * 256 + threadIdx.x;
    if (i < n) p[i] = 0;
}

__global__ void k_count(const int* __restrict__ dst, int* __restrict__ counts) {
    int e = blockIdx.x * 256 + threadIdx.x;
    if (e < N_EDGES) atomicAdd(&counts[dst[e]], 1);
}

__global__ __launch_bounds__(1024)
void k_scan(const int* __restrict__ counts, int* __restrict__ rowptr,
            int* __restrict__ cursor, float* __restrict__ dinv) {
    __shared__ int part[1024];
    const int CHUNK = (N_NODES + 1023) / 1024;
    int t = threadIdx.x;
    int beg = t * CHUNK;
    int end = min(beg + CHUNK, N_NODES);
    int s = 0;
    for (int i = beg; i < end; ++i) s += counts[i];
    part[t] = s;
    __syncthreads();
    for (int off = 1; off < 1024; off <<= 1) {
        int v = (t >= off) ? part[t - off] : 0;
        __syncthreads();
        part[t] += v;
        __syncthreads();
    }
    int excl = (t == 0) ? 0 : part[t - 1];
    for (int i = beg; i < end; ++i) {
        int c = counts[i];
        rowptr[i] = excl;
        cursor[i] = excl;
        dinv[i] = rsqrtf(1.0f + (float)c);
        excl += c;
    }
    if (t == 1023) rowptr[N_NODES] = part[1023];
}

__global__ void k_fill(const int* __restrict__ src, const int* __restrict__ dst,
                       int* __restrict__ cursor, int* __restrict__ csr_src) {
    int e = blockIdx.x * 256 + threadIdx.x;
    if (e < N_EDGES) {
        int d = dst[e];
        int pos = atomicAdd(&cursor[d], 1);
        csr_src[pos] = src[e];
    }
}

// ---------------- conversions ----------------
// gene rows: x[:,0:512] fp32 -> xt bf16
__global__ void k_copy_gene_bf(const float* __restrict__ x, unsigned short* __restrict__ xt) {
    int idx = blockIdx.x * 256 + threadIdx.x;  // N_GENE*64 threads, 8 cols each
    int row = idx >> 6, c8 = (idx & 63) * 8;
    if (row >= N_GENE) return;
    const float4* s = (const float4*)(x + (size_t)row * GOID_DIM + c8);
    float4 a = s[0], b = s[1];
    uint4 u;
    u.x = pack2(a.x, a.y); u.y = pack2(a.z, a.w);
    u.z = pack2(b.x, b.y); u.w = pack2(b.z, b.w);
    *(uint4*)(xt + (size_t)row * D_IN + c8) = u;
}

// flat fp32 -> bf16 (8 elems / thread)
__global__ void k_f2bf8(const float* __restrict__ src, unsigned short* __restrict__ dst, int n8) {
    int i = blockIdx.x * 256 + threadIdx.x;
    if (i >= n8) return;
    const float4* s = (const float4*)src;
    float4 a = s[2 * (size_t)i], b = s[2 * (size_t)i + 1];
    uint4 u;
    u.x = pack2(a.x, a.y); u.y = pack2(a.z, a.w);
    u.z = pack2(b.x, b.y); u.w = pack2(b.z, b.w);
    ((uint4*)dst)[i] = u;
}

// W (KxN fp32) -> Wt (NxK bf16)
__global__ void k_wt(const float* __restrict__ W, unsigned short* __restrict__ Wt,
                     int K, int N) {
    __shared__ float t[32][33];
    int k0 = blockIdx.y * 32, n0 = blockIdx.x * 32;
    int tx = threadIdx.x, ty = threadIdx.y;  // (32,8)
#pragma unroll
    for (int i = 0; i < 4; ++i)
        t[ty + i * 8][tx] = W[(size_t)(k0 + ty + i * 8) * N + n0 + tx];
    __syncthreads();
#pragma unroll
    for (int i = 0; i < 4; ++i)
        Wt[(size_t)(n0 + ty + i * 8) * K + k0 + tx] = f2bf(t[tx][ty + i * 8]);
}

// ---------------- bf16 MFMA GEMM: C(MxN) = A(MxK) @ Bt(NxK)^T ----------------
// EPI_BIAS_RELU: C[m*N+n] = relu(v + bias[n])
// EPI_CONV: dual output. cols [0,NH): C[m*NH+n] = v*rowscale[m]; cols [NH,2NH): C2[m*NH+n-NH] = v.
//           r-half blocks with bm >= Mr are skipped entirely (output unused).
#define EPI_BIAS_RELU 0
#define EPI_CONV 1

template <int EPI>
__global__ __launch_bounds__(256)
void k_gemm_bf(const unsigned short* __restrict__ A,
               const unsigned short* __restrict__ Bt,
               const float* __restrict__ bias,
               const float* __restrict__ rowscale,
               unsigned short* __restrict__ C,
               unsigned short* __restrict__ C2,
               int M, int N, int K, int NH, int Mr) {
    __shared__ unsigned short As[128 * 32];  // [row][k] row-major
    __shared__ unsigned short Bs[128 * 32];  // [col][k] row-major
    int tid = threadIdx.x;
    int l = tid & 63, w = tid >> 6;
    int bm = blockIdx.y * 128, bn = blockIdx.x * 128;

    if (EPI == EPI_CONV) {
        // whole block in the plain (r) half and beyond the needed rows -> dead output
        if (bn >= NH && bm >= Mr) return;
    }

    // staging: lane l of wave w covers rows w*16 + (l>>2) (+64 for round 1), k-chunk (l&3)*8
    int srow = w * 16 + (l >> 2);
    int sk = (l & 3) * 8;
    int am0 = min(bm + srow, M - 1);
    int am1 = min(bm + srow + 64, M - 1);
    const unsigned short* ag0 = A + (size_t)am0 * K + sk;
    const unsigned short* ag1 = A + (size_t)am1 * K + sk;
    const unsigned short* bg0 = Bt + (size_t)(bn + srow) * K + sk;
    const unsigned short* bg1 = Bt + (size_t)(bn + srow + 64) * K + sk;
    unsigned short* al0 = &As[w * 512];
    unsigned short* al1 = &As[2048 + w * 512];
    unsigned short* bl0 = &Bs[w * 512];
    unsigned short* bl1 = &Bs[2048 + w * 512];

    int wm = w & 1, wn = w >> 1;
    int row16 = l & 15, half = l >> 4;
    const unsigned short* Abase = &As[(wm * 64 + row16) * 32 + half * 8];
    const unsigned short* Bbase = &Bs[(wn * 64 + row16) * 32 + half * 8];

    v4f acc[4][4];
#pragma unroll
    for (int i = 0; i < 4; ++i)
#pragma unroll
        for (int j = 0; j < 4; ++j) acc[i][j] = (v4f){0.f, 0.f, 0.f, 0.f};

    for (int k0 = 0; k0 < K; k0 += 32) {
        gload_lds16(ag0, al0);
        gload_lds16(ag1, al1);
        gload_lds16(bg0, bl0);
        gload_lds16(bg1, bl1);
        ag0 += 32; ag1 += 32; bg0 += 32; bg1 += 32;
        __syncthreads();
        bf16x8 af[4], bf_[4];
#pragma unroll
        for (int t = 0; t < 4; ++t) {
            af[t] = *(const bf16x8*)(Abase + t * 16 * 32);
            bf_[t] = *(const bf16x8*)(Bbase + t * 16 * 32);
        }
#pragma unroll
        for (int i = 0; i < 4; ++i)
#pragma unroll
            for (int j = 0; j < 4; ++j)
                acc[i][j] = __builtin_amdgcn_mfma_f32_16x16x32_bf16(af[i], bf_[j], acc[i][j], 0, 0, 0);
        __syncthreads();
    }

#pragma unroll
    for (int mt = 0; mt < 4; ++mt) {
#pragma unroll
        for (int r = 0; r < 4; ++r) {
            int m = bm + wm * 64 + mt * 16 + half * 4 + r;
            if (m < M) {
                float sc = (EPI == EPI_CONV) ? rowscale[m] : 0.f;
#pragma unroll
                for (int nt = 0; nt < 4; ++nt) {
                    int n = bn + wn * 64 + nt * 16 + row16;
                    float v = acc[mt][nt][r];
                    if (EPI == EPI_BIAS_RELU) {
                        v = fmaxf(v + bias[n], 0.f);
                        C[(size_t)m * N + n] = f2bf(v);
                    } else {  // EPI_CONV
                        if (n < NH)
                            C[(size_t)m * NH + n] = f2bf(v * sc);
                        else
                            C2[(size_t)m * NH + (n - NH)] = f2bf(v);
                    }
                }
            }
        }
    }
}

// ---------------- conv1 aggregation + residual combine (F=512, bf16 out) ----------------
// out[i] = relu(dinv[i]*(sum_{src->i} hwS[src] + hwS[i]) + bc) + r[i] + br
// one wave per node, 16B gather per lane per edge, 2-way unrolled edge loop
__global__ void k_combine512(const unsigned short* __restrict__ hwS,
                             const unsigned short* __restrict__ rres,
                             const float* __restrict__ dinv,
                             const int* __restrict__ rowptr, const int* __restrict__ csr_src,
                             const float* __restrict__ bc, const float* __restrict__ br,
                             unsigned short* __restrict__ out) {
    int node = blockIdx.x;
    int c = threadIdx.x * 8;  // 64 threads x 8 cols
    int beg = rowptr[node], end = rowptr[node + 1];
    uint4 sv = *(const uint4*)(hwS + (size_t)node * HID1 + c);
    float a0, a1, a2, a3, a4, a5, a6, a7;
    unp2(sv.x, a0, a1); unp2(sv.y, a2, a3); unp2(sv.z, a4, a5); unp2(sv.w, a6, a7);
    int e = beg;
    for (; e + 2 <= end; e += 2) {
        int s0 = csr_src[e], s1 = csr_src[e + 1];
        uint4 v0 = *(const uint4*)(hwS + (size_t)s0 * HID1 + c);
        uint4 v1 = *(const uint4*)(hwS + (size_t)s1 * HID1 + c);
        float t0, t1;
        unp2(v0.x, t0, t1); a0 += t0; a1 += t1;
        unp2(v0.y, t0, t1); a2 += t0; a3 += t1;
        unp2(v0.z, t0, t1); a4 += t0; a5 += t1;
        unp2(v0.w, t0, t1); a6 += t0; a7 += t1;
        unp2(v1.x, t0, t1); a0 += t0; a1 += t1;
        unp2(v1.y, t0, t1); a2 += t0; a3 += t1;
        unp2(v1.z, t0, t1); a4 += t0; a5 += t1;
        unp2(v1.w, t0, t1); a6 += t0; a7 += t1;
    }
    if (e < end) {
        int s0 = csr_src[e];
        uint4 v0 = *(const uint4*)(hwS + (size_t)s0 * HID1 + c);
        float t0, t1;
        unp2(v0.x, t0, t1); a0 += t0; a1 += t1;
        unp2(v0.y, t0, t1); a2 += t0; a3 += t1;
        unp2(v0.z, t0, t1); a4 += t0; a5 += t1;
        unp2(v0.w, t0, t1); a6 += t0; a7 += t1;
    }
    float di = dinv[node];
    uint4 rv = *(const uint4*)(rres + (size_t)node * HID1 + c);
    float r0, r1, r2, r3, r4, r5, r6, r7;
    unp2(rv.x, r0, r1); unp2(rv.y, r2, r3); unp2(rv.z, r4, r5); unp2(rv.w, r6, r7);
    float4 vb0 = *(const float4*)&bc[c];
    float4 vb1 = *(const float4*)&bc[c + 4];
    float4 vq0 = *(const float4*)&br[c];
    float4 vq1 = *(const float4*)&br[c + 4];
    float o0 = fmaxf(fmaf(di, a0, vb0.x), 0.f) + r0 + vq0.x;
    float o1 = fmaxf(fmaf(di, a1, vb0.y), 0.f) + r1 + vq0.y;
    float o2 = fmaxf(fmaf(di, a2, vb0.z), 0.f) + r2 + vq0.z;
    float o3 = fmaxf(fmaf(di, a3, vb0.w), 0.f) + r3 + vq0.w;
    float o4 = fmaxf(fmaf(di, a4, vb1.x), 0.f) + r4 + vq1.x;
    float o5 = fmaxf(fmaf(di, a5, vb1.y), 0.f) + r5 + vq1.y;
    float o6 = fmaxf(fmaf(di, a6, vb1.z), 0.f) + r6 + vq1.z;
    float o7 = fmaxf(fmaf(di, a7, vb1.w), 0.f) + r7 + vq1.w;
    uint4 ov;
    ov.x = pack2(o0, o1); ov.y = pack2(o2, o3);
    ov.z = pack2(o4, o5); ov.w = pack2(o6, o7);
    *(uint4*)(out + (size_t)node * HID1 + c) = ov;
}

// ---------------- conv2 combine fused with final projection (F=256) ----------------
// h2_row = relu(dinv*(agg+self)+bc)+r+br computed in-register (one wave = full row),
// then out[node] = [h2_row, istj] @ W_f + b_f via shfl tree. Only gene nodes.
__global__ void k_combine_final(const unsigned short* __restrict__ hwS,
                                const unsigned short* __restrict__ rres,
                                const float* __restrict__ dinv,
                                const int* __restrict__ rowptr, const int* __restrict__ csr_src,
                                const float* __restrict__ bc, const float* __restrict__ br,
                                const float* __restrict__ istj,
                                const float* __restrict__ Wf, const float* __restrict__ bfv,
                                float* __restrict__ out) {
    int node = blockIdx.x;  // < N_GENE
    int t = threadIdx.x;    // 64 threads
    int c = t * 4;
    int beg = rowptr[node], end = rowptr[node + 1];
    uint2 sv = *(const uint2*)(hwS + (size_t)node * HID2 + c);
    float a0, a1, a2, a3;
    unp2(sv.x, a0, a1); unp2(sv.y, a2, a3);
    int e = beg;
    for (; e + 2 <= end; e += 2) {
        int s0 = csr_src[e], s1 = csr_src[e + 1];
        uint2 v0 = *(const uint2*)(hwS + (size_t)s0 * HID2 + c);
        uint2 v1 = *(const uint2*)(hwS + (size_t)s1 * HID2 + c);
        float t0, t1;
        unp2(v0.x, t0, t1); a0 += t0; a1 += t1;
        unp2(v0.y, t0, t1); a2 += t0; a3 += t1;
        unp2(v1.x, t0, t1); a0 += t0; a1 += t1;
        unp2(v1.y, t0, t1); a2 += t0; a3 += t1;
    }
    if (e < end) {
        int s0 = csr_src[e];
        uint2 v0 = *(const uint2*)(hwS + (size_t)s0 * HID2 + c);
        float t0, t1;
        unp2(v0.x, t0, t1); a0 += t0; a1 += t1;
        unp2(v0.y, t0, t1); a2 += t0; a3 += t1;
    }
    float di = dinv[node];
    uint2 rv = *(const uint2*)(rres + (size_t)node * HID2 + c);
    float r0, r1, r2, r3;
    unp2(rv.x, r0, r1); unp2(rv.y, r2, r3);
    float4 vb = *(const float4*)&bc[c];
    float4 vq = *(const float4*)&br[c];
    float o0 = fmaxf(fmaf(di, a0, vb.x), 0.f) + r0 + vq.x;
    float o1 = fmaxf(fmaf(di, a1, vb.y), 0.f) + r1 + vq.y;
    float o2 = fmaxf(fmaf(di, a2, vb.z), 0.f) + r2 + vq.z;
    float o3 = fmaxf(fmaf(di, a3, vb.w), 0.f) + r3 + vq.w;
    // final dot: Wf is [HID2+1][2] row-major. wa = {w0[c],w1[c],w0[c+1],w1[c+1]}
    float4 wa = *(const float4*)&Wf[2 * c];
    float4 wb = *(const float4*)&Wf[2 * c + 4];
    float s0 = o0 * wa.x + o1 * wa.z + o2 * wb.x + o3 * wb.z;
    float s1 = o0 * wa.y + o1 * wa.w + o2 * wb.y + o3 * wb.w;
    for (int off = 32; off > 0; off >>= 1) {
        s0 += __shfl_down(s0, off);
        s1 += __shfl_down(s1, off);
    }
    if (t == 0) {
        float it = istj[node];
        out[(size_t)node * 2 + 0] = s0 + it * Wf[2 * HID2] + bfv[0];
        out[(size_t)node * 2 + 1] = s1 + it * Wf[2 * HID2 + 1] + bfv[1];
    }
}

extern "C" void kernel_launch(void* const* d_in, const int* in_sizes, int n_in,
                              void* d_out, int out_size, void* d_ws, size_t ws_size,
                              hipStream_t stream) {
    const float* x     = (const float*)d_in[0];
    const int*   ei    = (const int*)d_in[1];
    const float* istj  = (const float*)d_in[2];
    const float* W_go1 = (const float*)d_in[4];
    const float* b_go1 = (const float*)d_in[5];
    const float* W_go2 = (const float*)d_in[6];
    const float* b_go2 = (const float*)d_in[7];
    const float* W_c1  = (const float*)d_in[8];
    const float* b_c1  = (const float*)d_in[9];
    const float* W_c2  = (const float*)d_in[10];
    const float* b_c2  = (const float*)d_in[11];
    const float* W_r1  = (const float*)d_in[12];
    const float* b_r1  = (const float*)d_in[13];
    const float* W_r2  = (const float*)d_in[14];
    const float* b_r2  = (const float*)d_in[15];
    const float* W_f   = (const float*)d_in[16];
    const float* b_f   = (const float*)d_in[17];
    float* out = (float*)d_out;

    char* w = (char*)d_ws;
    size_t off = 0;
    auto alloc = [&](size_t bytes) -> void* {
        void* p = w + off;
        off += (bytes + 255) & ~(size_t)255;
        return p;
    };
    // region A: xt bf16 (later h1 bf16, in place)
    unsigned short* xt_bf = (unsigned short*)alloc((size_t)N_NODES * D_IN * 2);
    // region B: hwS bf16; early: g1 bf16 (10000*1024 <= 50000*512)
    unsigned short* bufB = (unsigned short*)alloc((size_t)N_NODES * D_IN * 2);
    unsigned short* g1_bf = bufB;
    // region C: r bf16; early: xg bf16 (10000*4096 > 50000*512 -> size for xg)
    unsigned short* bufC = (unsigned short*)alloc((size_t)N_GOID * GOID_DIM * 2);
    unsigned short* xg_bf = bufC;
    // weights bf16 transposed (NxK); conv weight pairs concatenated along N
    unsigned short* Wgo1t = (unsigned short*)alloc((size_t)GO_HID * GOID_DIM * 2);
    unsigned short* Wgo2t = (unsigned short*)alloc((size_t)D_IN * GO_HID * 2);
    unsigned short* Wcr1t = (unsigned short*)alloc((size_t)(2 * HID1) * D_IN * 2);
    unsigned short* Wcr2t = (unsigned short*)alloc((size_t)(2 * HID2) * HID1 * 2);
    float* dinv = (float*)alloc((size_t)N_NODES * 4);
    int* counts = (int*)alloc((size_t)N_NODES * 4);
    int* rowptr = (int*)alloc((size_t)(N_NODES + 1) * 4);
    int* cursor = (int*)alloc((size_t)N_NODES * 4);
    int* csr    = (int*)alloc((size_t)N_EDGES * 4);

    const int* srcp = ei;
    const int* dstp = ei + N_EDGES;

    // CSR + degree norm
    k_zero<<<(N_NODES + 255) / 256, 256, 0, stream>>>(counts, N_NODES);
    k_count<<<(N_EDGES + 255) / 256, 256, 0, stream>>>(dstp, counts);
    k_scan<<<1, 1024, 0, stream>>>(counts, rowptr, cursor, dinv);
    k_fill<<<(N_EDGES + 255) / 256, 256, 0, stream>>>(srcp, dstp, cursor, csr);

    // conversions
    k_copy_gene_bf<<<(N_GENE * 64) / 256, 256, 0, stream>>>(x, xt_bf);
    k_f2bf8<<<(N_GOID * GOID_DIM / 8 + 255) / 256, 256, 0, stream>>>(
        x + (size_t)N_GENE * GOID_DIM, xg_bf, N_GOID * GOID_DIM / 8);
    k_wt<<<dim3(GO_HID / 32, GOID_DIM / 32), dim3(32, 8), 0, stream>>>(W_go1, Wgo1t, GOID_DIM, GO_HID);
    k_wt<<<dim3(D_IN / 32, GO_HID / 32), dim3(32, 8), 0, stream>>>(W_go2, Wgo2t, GO_HID, D_IN);
    k_wt<<<dim3(HID1 / 32, D_IN / 32), dim3(32, 8), 0, stream>>>(W_c1, Wcr1t, D_IN, HID1);
    k_wt<<<dim3(HID1 / 32, D_IN / 32), dim3(32, 8), 0, stream>>>(
        W_r1, Wcr1t + (size_t)HID1 * D_IN, D_IN, HID1);
    k_wt<<<dim3(HID2 / 32, HID1 / 32), dim3(32, 8), 0, stream>>>(W_c2, Wcr2t, HID1, HID2);
    k_wt<<<dim3(HID2 / 32, HID1 / 32), dim3(32, 8), 0, stream>>>(
        W_r2, Wcr2t + (size_t)HID2 * HID1, HID1, HID2);

    // GOID MLP
    k_gemm_bf<EPI_BIAS_RELU><<<dim3(GO_HID / 128, (N_GOID + 127) / 128), 256, 0, stream>>>(
        xg_bf, Wgo1t, b_go1, nullptr, g1_bf, nullptr, N_GOID, GO_HID, GOID_DIM, 0, 0);
    k_gemm_bf<EPI_BIAS_RELU><<<dim3(D_IN / 128, (N_GOID + 127) / 128), 256, 0, stream>>>(
        g1_bf, Wgo2t, b_go2, nullptr, xt_bf + (size_t)N_GENE * D_IN, nullptr,
        N_GOID, D_IN, GO_HID, 0, 0);

    // conv1: fused c+r GEMM (N = 2*HID1), scaled half -> bufB, plain half -> bufC
    k_gemm_bf<EPI_CONV><<<dim3(2 * HID1 / 128, (N_NODES + 127) / 128), 256, 0, stream>>>(
        xt_bf, Wcr1t, nullptr, dinv, bufB, bufC, N_NODES, 2 * HID1, D_IN, HID1, N_NODES);
    k_combine512<<<N_NODES, HID1 / 8, 0, stream>>>(
        bufB, bufC, dinv, rowptr, csr, b_c1, b_r1, xt_bf);

    // conv2: fused c+r GEMM; r-half only needed for gene rows (Mr = N_GENE)
    k_gemm_bf<EPI_CONV><<<dim3(2 * HID2 / 128, (N_NODES + 127) / 128), 256, 0, stream>>>(
        xt_bf, Wcr2t, nullptr, dinv, bufB, bufC, N_NODES, 2 * HID2, HID1, HID2, N_GENE);

    // conv2 combine fused with final projection, gene rows only
    k_combine_final<<<N_GENE, HID2 / 4, 0, stream>>>(
        bufB, bufC, dinv, rowptr, csr, b_c2, b_r2, istj, W_f, b_f, out);
}